// Round 2
// baseline (1788.614 us; speedup 1.0000x reference)
//
#include <hip/hip_runtime.h>
#include <hip/hip_cooperative_groups.h>
#include <math.h>

namespace cg = cooperative_groups;

// FractalOpponent on MI355X: single cooperative megakernel.
// The whole recursive tree (max 5 nodes + 3 finalizes) runs inside one kernel;
// grid.sync() separates split-K GEMV stages; control flow (steps) is computed
// uniformly & deterministically by every block.

#define H 2048
#define NBLK 256
#define TPB 512

struct KParams {
  const float *x, *h0, *c0;
  const float *Wv, *Wo, *Wih, *Whh, *b_lstm;
  const float *router_w, *router_b, *expert_w, *expert_b;
  const float *dr_w, *dr_b, *ram_w, *ram_b, *ag_w, *ag_b;
  float* out;
  float* ws;
};

// y[j] += sum_i x[i] * W[i,j].  x = concat(xA,xB) split at splitPt.
// All NBLK blocks participate: G = N/256 column groups, KS = NBLK/G k-slices.
// 8 waves/block each cover chunk/8 rows; lane covers 4 consecutive columns.
__device__ __forceinline__ void gemv(const float* xA, const float* xB, int splitPt,
                                     const float* __restrict__ W, float* __restrict__ y,
                                     int K, int N, int expertMode, float4* red)
{
  const int tid  = threadIdx.x;
  const int lane = tid & 63;
  const int w    = tid >> 6;
  const int G    = N >> 8;
  const int KS   = NBLK / G;
  const int g    = (int)blockIdx.x % G;
  const int s    = (int)blockIdx.x / G;
  const int chunk = K / KS;
  const int rpw   = chunk >> 3;
  const int i0    = s * chunk + w * rpw;
  const int j     = (g << 8) + (lane << 2);

  const float* Wp;
  int stride;
  if (expertMode) {
    const int e = j >> 11, k = j & (H - 1);
    Wp = W + ((size_t)e << 22) + (size_t)i0 * H + k;
    stride = H;
  } else {
    Wp = W + (size_t)i0 * N + j;
    stride = N;
  }
  float ax = 0.f, ay = 0.f, az = 0.f, aw = 0.f;
  for (int t = 0; t < rpw; ++t) {
    const int i = i0 + t;
    const float xi = (i < splitPt) ? xA[i] : xB[i - splitPt];
    const float4 wv = *reinterpret_cast<const float4*>(Wp);
    ax = fmaf(xi, wv.x, ax); ay = fmaf(xi, wv.y, ay);
    az = fmaf(xi, wv.z, az); aw = fmaf(xi, wv.w, aw);
    Wp += stride;
  }
  red[tid] = make_float4(ax, ay, az, aw);
  __syncthreads();
  if (tid < 64) {
    float4 a = red[tid];
    for (int q = 1; q < 8; ++q) {
      float4 b = red[q * 64 + tid];
      a.x += b.x; a.y += b.y; a.z += b.z; a.w += b.w;
    }
    atomicAdd(&y[j + 0], a.x);
    atomicAdd(&y[j + 1], a.y);
    atomicAdd(&y[j + 2], a.z);
    atomicAdd(&y[j + 3], a.w);
  }
  __syncthreads();
}

// Block-wide float4 sum; bitwise-identical across blocks (fixed tree order).
__device__ __forceinline__ float4 block_reduce4(float4 v, float4* red)
{
  red[threadIdx.x] = v;
  __syncthreads();
  for (int off = TPB / 2; off > 0; off >>= 1) {
    if (threadIdx.x < off) {
      float4 b = red[threadIdx.x + off];
      red[threadIdx.x].x += b.x; red[threadIdx.x].y += b.y;
      red[threadIdx.x].z += b.z; red[threadIdx.x].w += b.w;
    }
    __syncthreads();
  }
  float4 r = red[0];
  __syncthreads();
  return r;
}

__device__ __forceinline__ float sigm(float v) { return 1.f / (1.f + expf(-v)); }

// One tree node. Writes so, cs, hp (global). Returns steps (0..maxSteps), uniform.
__device__ int node_run(cg::grid_group& grid, const KParams& p,
                        const float* hv, const float* cv,
                        float* so, float* cs, float* hp,
                        int maxSteps, float4* red, float* h2l)
{
  const int tid  = threadIdx.x;
  const int gtid = (int)blockIdx.x * TPB + tid;
  const int gsz  = NBLK * TPB;
  float* t_hv  = p.ws;
  float* attn  = p.ws + H;
  float* gates = p.ws + 2 * H;
  float* eo    = p.ws + 6 * H;

  // init region: accumulators get their bias values
  for (int i = gtid; i < H; i += gsz) { t_hv[i] = 0.f; attn[i] = 0.f; }
  for (int i = gtid; i < 4 * H; i += gsz) { gates[i] = p.b_lstm[i]; eo[i] = p.expert_b[i]; }
  grid.sync();

  // stage A: t_hv += h @ Wv ; gates += x @ Wih   (independent, one sync)
  gemv(hv, hv, H, p.Wv, t_hv, H, H, 0, red);
  gemv(p.x, p.x, H, p.Wih, gates, H, 4 * H, 0, red);
  grid.sync();

  // stage B: attn += t_hv @ Wo
  gemv(t_hv, t_hv, H, p.Wo, attn, H, H, 0, red);
  grid.sync();

  // stage C: gates += attn @ Whh
  gemv(attn, attn, H, p.Whh, gates, H, 4 * H, 0, red);
  grid.sync();

  // stage D: LSTM (each block computes full h2 locally), router softmax,
  //          expert GEMV from LDS h2; block 0 persists so/cs.
  for (int i = tid; i < H; i += TPB) {
    const float gi = gates[i], gf = gates[H + i], gg = gates[2 * H + i], go = gates[3 * H + i];
    const float c2 = sigm(gf) * cv[i] + sigm(gi) * tanhf(gg);
    const float h2 = sigm(go) * tanhf(c2);
    h2l[i] = h2;
    if (blockIdx.x == 0) { so[i] = h2; cs[i] = c2; }
  }
  __syncthreads();
  float4 rs = make_float4(0.f, 0.f, 0.f, 0.f);
  for (int i = tid; i < H; i += TPB) {
    const float hh = h2l[i];
    const float4 rw = *reinterpret_cast<const float4*>(p.router_w + i * 4);
    rs.x = fmaf(hh, rw.x, rs.x); rs.y = fmaf(hh, rw.y, rs.y);
    rs.z = fmaf(hh, rw.z, rs.z); rs.w = fmaf(hh, rw.w, rs.w);
  }
  rs = block_reduce4(rs, red);
  const float l0 = rs.x + p.router_b[0], l1 = rs.y + p.router_b[1];
  const float l2 = rs.z + p.router_b[2], l3 = rs.w + p.router_b[3];
  const float m  = fmaxf(fmaxf(l0, l1), fmaxf(l2, l3));
  const float e0 = expf(l0 - m), e1 = expf(l1 - m), e2 = expf(l2 - m), e3 = expf(l3 - m);
  const float inv = 1.f / (e0 + e1 + e2 + e3);
  const float p0 = e0 * inv, p1 = e1 * inv, p2 = e2 * inv, p3 = e3 * inv;
  gemv(h2l, h2l, H, p.expert_w, eo, H, 4 * H, 1, red);
  grid.sync();

  // stage E: hp[j] = sum_e p_e * eo[e][j]   (8 columns per block)
  {
    const int jb = (int)blockIdx.x * (H / NBLK);
    if (tid < H / NBLK) {
      const int j = jb + tid;
      hp[j] = p0 * eo[j] + p1 * eo[H + j] + p2 * eo[2 * H + j] + p3 * eo[3 * H + j];
    }
  }
  grid.sync();

  if (maxSteps <= 0) return 0;

  // depth decision: every block redundantly reduces hp @ dr_w (deterministic)
  float4 d = make_float4(0.f, 0.f, 0.f, 0.f);
  for (int i = tid; i < H; i += TPB) {
    const float hval = hp[i];
    d.x = fmaf(hval, p.dr_w[i * 3 + 0], d.x);
    d.y = fmaf(hval, p.dr_w[i * 3 + 1], d.y);
    d.z = fmaf(hval, p.dr_w[i * 3 + 2], d.z);
  }
  d = block_reduce4(d, red);
  const float L0 = d.x + p.dr_b[0], L1 = d.y + p.dr_b[1], L2 = d.z + p.dr_b[2];
  int ch = 0; float bv = L0;
  if (L1 > bv) { bv = L1; ch = 1; }
  if (L2 > bv) { bv = L2; ch = 2; }
  return (ch < maxSteps) ? ch : maxSteps;
}

// Depth-1 finalize (single child, damping 0.25): writes rhbuf (gated mix).
__device__ void finalize1(cg::grid_group& grid, const KParams& p,
                          const float* hp_node, const float* rh_child,
                          float* hn, float* agg, float* anchor, float* gacc,
                          float* rhbuf, float4* red)
{
  const int gtid = (int)blockIdx.x * TPB + threadIdx.x;
  const int gsz  = NBLK * TPB;
  for (int i = gtid; i < H; i += gsz) {
    const float h0 = hp_node[i];
    const float hni = h0 + 0.25f * (rh_child[i] - h0);
    hn[i] = hni;
    agg[i] = h0 - 0.5f * hni;
    anchor[i] = p.ram_b[i];
    gacc[i] = p.ag_b[i];
  }
  grid.sync();
  gemv(agg, hp_node, H, p.ram_w, anchor, 2 * H, H, 0, red);
  grid.sync();
  gemv(hn, anchor, H, p.ag_w, gacc, 2 * H, H, 0, red);
  grid.sync();
  for (int i = gtid; i < H; i += gsz) {
    const float g = sigm(gacc[i]);
    rhbuf[i] = g * anchor[i] + (1.f - g) * hn[i];
  }
  grid.sync();
}

__global__ __launch_bounds__(TPB, 2) void mega(KParams p)
{
  cg::grid_group grid = cg::this_grid();
  __shared__ float4 red[TPB];
  __shared__ float h2l[H];
  const int gtid = (int)blockIdx.x * TPB + threadIdx.x;
  const int gsz  = NBLK * TPB;

  float* ws = p.ws;
  float* base   = ws + 10 * H;     // after t_hv/attn/gates/eo scratch
  float* so0 = base;          float* cs0 = base + H;      float* hp0 = base + 2 * H;
  float* so1 = base + 3 * H;  float* cs1 = base + 4 * H;  float* hp1 = base + 5 * H;
  float* so2 = base + 6 * H;  float* cs2 = base + 7 * H;  float* hp2 = base + 8 * H;
  float* so3 = base + 9 * H;  float* cs3 = base + 10 * H; float* hp3 = base + 11 * H;
  float* so4 = base + 12 * H; float* cs4 = base + 13 * H; float* hp4 = base + 14 * H;
  float* hn1    = base + 15 * H;
  float* agg    = base + 16 * H;
  float* anchor = base + 17 * H;
  float* gacc   = base + 18 * H;
  float* rh1buf = base + 19 * H;
  float* rh3buf = base + 20 * H;

  // ---- N0 (depth 0) ----
  const int s0 = node_run(grid, p, p.h0, p.c0, so0, cs0, hp0, 2, red, h2l);

  if (s0 == 0) {
    for (int i = gtid; i < H; i += gsz) {
      p.out[i] = so0[i]; p.out[H + i] = hp0[i]; p.out[2 * H + i] = cs0[i];
    }
    return;
  }

  // ---- first depth-0 child: N1 (depth 1) ----
  const float *rf1p, *rh1p, *rc1p;
  {
    const int s1 = node_run(grid, p, hp0, cs0, so1, cs1, hp1, 1, red, h2l);
    if (s1 >= 1) {
      node_run(grid, p, hp1, cs1, so2, cs2, hp2, 0, red, h2l);  // N2 leaf
      finalize1(grid, p, hp1, hp2, hn1, agg, anchor, gacc, rh1buf, red);
      rf1p = so2; rh1p = rh1buf; rc1p = cs2;
    } else {
      rf1p = so1; rh1p = hp1; rc1p = cs1;
    }
  }
  // depth-0 damping = 1 -> h_next(1) = rh1p (no copy needed)

  const float *rf3p = rf1p, *rh3p = rh1p, *rc3p = rc1p;
  if (s0 >= 2) {
    // ---- second depth-0 child: N3 (depth 1), inputs (rh1p, rc1p) ----
    const int s3 = node_run(grid, p, rh1p, rc1p, so3, cs3, hp3, 1, red, h2l);
    if (s3 >= 1) {
      node_run(grid, p, hp3, cs3, so4, cs4, hp4, 0, red, h2l);  // N4 leaf
      finalize1(grid, p, hp3, hp4, hn1, agg, anchor, gacc, rh3buf, red);
      rf3p = so4; rh3p = rh3buf; rc3p = cs4;
    } else {
      rf3p = so3; rh3p = hp3; rc3p = cs3;
    }
  }

  // ---- N0 finalize ----
  // states = [hp0, rh1p] (+ rh3p if s0==2); h_cur = last state; final/c from last child
  const float* rhLast = (s0 >= 2) ? rh3p : rh1p;
  const float* rfLast = (s0 >= 2) ? rf3p : rf1p;
  const float* rcLast = (s0 >= 2) ? rc3p : rc1p;
  for (int i = gtid; i < H; i += gsz) {
    float ag = hp0[i] - 0.5f * rh1p[i];
    if (s0 >= 2) ag += (1.f / 3.f) * rh3p[i];
    agg[i] = ag;
    anchor[i] = p.ram_b[i];
    gacc[i] = p.ag_b[i];
    p.out[i] = rfLast[i];
    p.out[2 * H + i] = rcLast[i];
  }
  grid.sync();
  gemv(agg, hp0, H, p.ram_w, anchor, 2 * H, H, 0, red);
  grid.sync();
  gemv(rhLast, anchor, H, p.ag_w, gacc, 2 * H, H, 0, red);
  grid.sync();
  for (int i = gtid; i < H; i += gsz) {
    const float g = sigm(gacc[i]);
    p.out[H + i] = g * anchor[i] + (1.f - g) * rhLast[i];
  }
}

extern "C" void kernel_launch(void* const* d_in, const int* in_sizes, int n_in,
                              void* d_out, int out_size, void* d_ws, size_t ws_size,
                              hipStream_t stream) {
  KParams p;
  p.x        = (const float*)d_in[0];
  p.h0       = (const float*)d_in[1];
  p.c0       = (const float*)d_in[2];
  p.Wv       = (const float*)d_in[5];
  p.Wo       = (const float*)d_in[6];
  p.Wih      = (const float*)d_in[7];
  p.Whh      = (const float*)d_in[8];
  p.b_lstm   = (const float*)d_in[9];
  p.router_w = (const float*)d_in[10];
  p.router_b = (const float*)d_in[11];
  p.expert_w = (const float*)d_in[12];
  p.expert_b = (const float*)d_in[13];
  p.dr_w     = (const float*)d_in[14];
  p.dr_b     = (const float*)d_in[15];
  p.ram_w    = (const float*)d_in[16];
  p.ram_b    = (const float*)d_in[17];
  p.ag_w     = (const float*)d_in[18];
  p.ag_b     = (const float*)d_in[19];
  p.out      = (float*)d_out;
  p.ws       = (float*)d_ws;

  void* args[] = { &p };
  hipLaunchCooperativeKernel((const void*)mega, dim3(NBLK), dim3(TPB), args, 0, stream);
}

// Round 3
// 406.198 us; speedup vs baseline: 4.4033x; 4.4033x over previous
//
#include <hip/hip_runtime.h>
#include <math.h>

// FractalOpponent on MI355X, round 3: stream-sequenced predicated kernels.
// Key changes vs round 1: x@Wih+b hoisted out of the 5 nodes (node-invariant),
// LSTM fused into expert GEMV, Ramanujan-prep fused into leaf combine,
// single upfront init, argmax predicates evaluated inline from logit slots.

#define H 2048

// ---- ws layout (floats) ----
#define DL0 0
#define DL1 4
#define DL3 8
#define GT  16            // gates_template[8192]
#define NODE_BASE (16 + 8192)
#define NODESZ 26624      // t_hv 2048 | attn 2048 | gates 8192 | eo 8192 | so 2048 | cs 2048 | hp 2048
#define O_THV   0
#define O_ATTN  2048
#define O_GATES 4096
#define O_EO    12288
#define O_SO    20480
#define O_CS    22528
#define O_HP    24576
#define FIN_BASE (NODE_BASE + 5 * NODESZ)
#define FINSZ 8192        // hn 2048 | agg 2048 | anchor 2048 | gacc 2048
#define O_HN     0
#define O_AGG    2048
#define O_ANCHOR 4096
#define O_GACC   6144
#define RH1 (FIN_BASE + 3 * FINSZ)
#define RF1 (RH1 + 2048)
#define RC1 (RH1 + 4096)

__device__ __forceinline__ float sigm(float v) { return 1.f / (1.f + expf(-v)); }

__device__ __forceinline__ int dsteps(const float* dl, int maxSteps) {
  float l0 = dl[0], l1 = dl[1], l2 = dl[2];
  int ch = 0; float bv = l0;
  if (l1 > bv) { bv = l1; ch = 1; }
  if (l2 > bv) { bv = l2; ch = 2; }
  return ch < maxSteps ? ch : maxSteps;
}

__device__ __forceinline__ bool pred_ok(const float* dlA, int maxA, int needA,
                                        const float* dlB, int maxB, int needB) {
  if (dlA && dsteps(dlA, maxA) < needA) return false;
  if (dlB && dsteps(dlB, maxB) < needB) return false;
  return true;
}

__global__ void k_init(float* ws, const float* b_lstm, const float* expert_b,
                       const float* ram_b, const float* ag_b, const float* dr_b) {
  const int gtid = blockIdx.x * 256 + threadIdx.x;
  const int gsz = gridDim.x * 256;
  if (gtid < 3) { ws[DL0 + gtid] = dr_b[gtid]; ws[DL1 + gtid] = dr_b[gtid]; ws[DL3 + gtid] = dr_b[gtid]; }
  for (int i = gtid; i < 8192; i += gsz) ws[GT + i] = b_lstm[i];
  for (int n = 0; n < 5; ++n) {
    float* nb = ws + NODE_BASE + n * NODESZ;
    for (int i = gtid; i < 4096; i += gsz) nb[O_THV + i] = 0.f;      // t_hv + attn
    for (int i = gtid; i < 8192; i += gsz) nb[O_EO + i] = expert_b[i];
  }
  for (int f = 0; f < 3; ++f) {
    float* fb = ws + FIN_BASE + f * FINSZ;
    for (int i = gtid; i < 2048; i += gsz) { fb[O_ANCHOR + i] = ram_b[i]; fb[O_GACC + i] = ag_b[i]; }
  }
}

// y[j] += sum_i x[i]*W[i,j]; x = concat(xA,xB) at splitPt. Grid (N/256)*KS, 256 thr.
// Optional side duty: copy copyN floats copySrc->copyDst (done by low blocks).
__global__ void k_gemv(const float* __restrict__ xA, const float* __restrict__ xB, int splitPt,
                       const float* __restrict__ W, float* __restrict__ y,
                       int K, int N, int KS,
                       const float* dlA, int maxA, int needA,
                       const float* dlB, int maxB, int needB,
                       const float* copySrc, float* copyDst, int copyN)
{
  if (!pred_ok(dlA, maxA, needA, dlB, maxB, needB)) return;
  const int tid = threadIdx.x, lane = tid & 63, tsub = tid >> 6;
  if (copySrc) {
    int gid = blockIdx.x * 256 + tid;
    if (gid < copyN) copyDst[gid] = copySrc[gid];
  }
  const int G = N >> 8;
  const int g = blockIdx.x % G;
  const int s = blockIdx.x / G;
  const int chunk = K / KS, len = chunk >> 2;
  const int i0 = s * chunk + tsub * len;
  const int j = (g << 8) + (lane << 2);
  const float* Wp = W + (size_t)i0 * N + j;
  float ax = 0.f, ay = 0.f, az = 0.f, aw = 0.f;
  for (int t = 0; t < len; ++t) {
    const int i = i0 + t;
    const float xi = (i < splitPt) ? xA[i] : xB[i - splitPt];
    const float4 wv = *reinterpret_cast<const float4*>(Wp);
    ax = fmaf(xi, wv.x, ax); ay = fmaf(xi, wv.y, ay);
    az = fmaf(xi, wv.z, az); aw = fmaf(xi, wv.w, aw);
    Wp += N;
  }
  __shared__ float4 red[256];
  red[tid] = make_float4(ax, ay, az, aw);
  __syncthreads();
  if (tsub == 0) {
    float4 a = red[tid], b = red[tid + 64], c = red[tid + 128], d = red[tid + 192];
    atomicAdd(&y[j + 0], a.x + b.x + c.x + d.x);
    atomicAdd(&y[j + 1], a.y + b.y + c.y + d.y);
    atomicAdd(&y[j + 2], a.z + b.z + c.z + d.z);
    atomicAdd(&y[j + 3], a.w + b.w + c.w + d.w);
  }
}

// Expert GEMV with fused LSTM: each block derives its h2 K-slice from gates/c_in.
// Grid 512 (= 32 col-groups x 16 K-slices), 256 thr. g==0 blocks persist so/cs.
__global__ void k_expert(const float* __restrict__ gates, const float* __restrict__ c_in,
                         const float* __restrict__ Wex, float* __restrict__ eo,
                         float* so, float* cs,
                         const float* dlA, int maxA, int needA,
                         const float* dlB, int maxB, int needB)
{
  if (!pred_ok(dlA, maxA, needA, dlB, maxB, needB)) return;
  const int tid = threadIdx.x, lane = tid & 63, w = tid >> 6;
  const int g = blockIdx.x & 31, s = blockIdx.x >> 5;
  const int i0 = s * 128;
  __shared__ float h2s[128];
  if (tid < 128) {
    const int i = i0 + tid;
    const float gi = gates[i], gf = gates[H + i], gg = gates[2 * H + i], go = gates[3 * H + i];
    const float c2 = sigm(gf) * c_in[i] + sigm(gi) * tanhf(gg);
    const float h2 = sigm(go) * tanhf(c2);
    h2s[tid] = h2;
    if (g == 0) { so[i] = h2; cs[i] = c2; }
  }
  __syncthreads();
  const int j = (g << 8) + (lane << 2);
  const int e = j >> 11, k = j & (H - 1);
  const float* Wp = Wex + ((size_t)e << 22) + (size_t)(i0 + w * 32) * H + k;
  float ax = 0.f, ay = 0.f, az = 0.f, aw = 0.f;
  for (int t = 0; t < 32; ++t) {
    const float xi = h2s[w * 32 + t];
    const float4 wv = *reinterpret_cast<const float4*>(Wp);
    ax = fmaf(xi, wv.x, ax); ay = fmaf(xi, wv.y, ay);
    az = fmaf(xi, wv.z, az); aw = fmaf(xi, wv.w, aw);
    Wp += H;
  }
  __shared__ float4 red[256];
  red[tid] = make_float4(ax, ay, az, aw);
  __syncthreads();
  if (w == 0) {
    float4 a = red[tid], b = red[tid + 64], c = red[tid + 128], d = red[tid + 192];
    atomicAdd(&eo[j + 0], a.x + b.x + c.x + d.x);
    atomicAdd(&eo[j + 1], a.y + b.y + c.y + d.y);
    atomicAdd(&eo[j + 2], a.z + b.z + c.z + d.z);
    atomicAdd(&eo[j + 3], a.w + b.w + c.w + d.w);
  }
}

// Router softmax + hp. Non-leaf: write hp + atomic depth-logit partials.
// Leaf: fuse parent's Ramanujan prep (hn, agg). Grid 8 blocks x 256.
template <int LEAF>
__global__ void k_combine(const float* __restrict__ h2,
                          const float* __restrict__ router_w, const float* __restrict__ router_b,
                          const float* __restrict__ eo,
                          float* hp_out, float* dl, const float* __restrict__ dr_w,
                          const float* php, float damping, float* hn_out, float* agg_out,
                          const float* dlA, int maxA, int needA,
                          const float* dlB, int maxB, int needB)
{
  if (!pred_ok(dlA, maxA, needA, dlB, maxB, needB)) return;
  const int tid = threadIdx.x;
  float r0 = 0.f, r1 = 0.f, r2 = 0.f, r3 = 0.f;
  for (int i = tid; i < H; i += 256) {
    const float hh = h2[i];
    const float4 rw = *reinterpret_cast<const float4*>(router_w + i * 4);
    r0 = fmaf(hh, rw.x, r0); r1 = fmaf(hh, rw.y, r1);
    r2 = fmaf(hh, rw.z, r2); r3 = fmaf(hh, rw.w, r3);
  }
  __shared__ float4 red[256];
  red[tid] = make_float4(r0, r1, r2, r3);
  __syncthreads();
  for (int off = 128; off > 0; off >>= 1) {
    if (tid < off) {
      float4 b = red[tid + off];
      red[tid].x += b.x; red[tid].y += b.y; red[tid].z += b.z; red[tid].w += b.w;
    }
    __syncthreads();
  }
  const float4 L = red[0];
  __syncthreads();
  const float l0 = L.x + router_b[0], l1 = L.y + router_b[1];
  const float l2 = L.z + router_b[2], l3 = L.w + router_b[3];
  const float m = fmaxf(fmaxf(l0, l1), fmaxf(l2, l3));
  const float e0 = expf(l0 - m), e1 = expf(l1 - m), e2 = expf(l2 - m), e3 = expf(l3 - m);
  const float inv = 1.f / (e0 + e1 + e2 + e3);
  const float p0 = e0 * inv, p1 = e1 * inv, p2 = e2 * inv, p3 = e3 * inv;
  const int jj = blockIdx.x * 256 + tid;
  const float v = p0 * eo[jj] + p1 * eo[H + jj] + p2 * eo[2 * H + jj] + p3 * eo[3 * H + jj];
  if (LEAF) {
    const float h0 = php[jj];
    const float hn = h0 + damping * (v - h0);
    hn_out[jj] = hn;
    agg_out[jj] = h0 - 0.5f * hn;
  } else {
    hp_out[jj] = v;
    const float d0 = v * dr_w[jj * 3 + 0];
    const float d1 = v * dr_w[jj * 3 + 1];
    const float d2 = v * dr_w[jj * 3 + 2];
    red[tid] = make_float4(d0, d1, d2, 0.f);
    __syncthreads();
    for (int off = 128; off > 0; off >>= 1) {
      if (tid < off) {
        float4 b = red[tid + off];
        red[tid].x += b.x; red[tid].y += b.y; red[tid].z += b.z;
      }
      __syncthreads();
    }
    if (tid == 0) {
      atomicAdd(&dl[0], red[0].x);
      atomicAdd(&dl[1], red[0].y);
      atomicAdd(&dl[2], red[0].z);
    }
  }
}

// N1 result select: rh1/rf1/rc1 from gated-finalize (s1==1) or raw node (s1==0).
__global__ void k_fsel(const float* dlC, int maxC,
                       const float* gacc, const float* anchor, const float* hn,
                       const float* soL, const float* csL,
                       const float* hpN, const float* soN, const float* csN,
                       float* rh, float* rf, float* rc,
                       const float* dlA, int maxA, int needA)
{
  if (dlA && dsteps(dlA, maxA) < needA) return;
  const int jj = blockIdx.x * 256 + threadIdx.x;
  if (dsteps(dlC, maxC) >= 1) {
    const float gv = sigm(gacc[jj]);
    rh[jj] = gv * anchor[jj] + (1.f - gv) * hn[jj];
    rf[jj] = soL[jj]; rc[jj] = csL[jj];
  } else {
    rh[jj] = hpN[jj]; rf[jj] = soN[jj]; rc[jj] = csN[jj];
  }
}

// Tail 1 (pred s0>=1): N3 result select (local), N0 Ramanujan prep, out F/C writes.
__global__ void k_tail1(const float* dl0p, const float* dl3p,
                        const float* rh1, const float* rf1, const float* rc1,
                        const float* gacc3, const float* anchor3, const float* hn3,
                        const float* so4, const float* cs4,
                        const float* hp3, const float* so3, const float* cs3,
                        const float* hp0,
                        float* agg0, float* hcur0, float* outF, float* outC)
{
  const int s0v = dsteps(dl0p, 2);
  if (s0v < 1) return;
  const int jj = blockIdx.x * 256 + threadIdx.x;
  float rh3 = 0.f, rf3 = 0.f, rc3 = 0.f;
  if (s0v >= 2) {
    if (dsteps(dl3p, 1) >= 1) {
      const float gv = sigm(gacc3[jj]);
      rh3 = gv * anchor3[jj] + (1.f - gv) * hn3[jj];
      rf3 = so4[jj]; rc3 = cs4[jj];
    } else { rh3 = hp3[jj]; rf3 = so3[jj]; rc3 = cs3[jj]; }
  }
  const float r1 = rh1[jj];
  float ag = hp0[jj] - 0.5f * r1;
  float hc, oF, oC;
  if (s0v >= 2) { ag += (1.f / 3.f) * rh3; hc = rh3; oF = rf3; oC = rc3; }
  else { hc = r1; oF = rf1[jj]; oC = rc1[jj]; }
  agg0[jj] = ag; hcur0[jj] = hc; outF[jj] = oF; outC[jj] = oC;
}

// Tail 2 (unconditional): final gated h (s0>=1) or full leaf passthrough (s0==0).
__global__ void k_tail2(const float* dl0p,
                        const float* so0, const float* hp0, const float* cs0,
                        const float* gacc0, const float* anchor0, const float* hcur0,
                        float* out)
{
  const int s0v = dsteps(dl0p, 2);
  const int jj = blockIdx.x * 256 + threadIdx.x;
  if (s0v == 0) {
    out[jj] = so0[jj]; out[H + jj] = hp0[jj]; out[2 * H + jj] = cs0[jj];
  } else {
    const float gv = sigm(gacc0[jj]);
    out[H + jj] = gv * anchor0[jj] + (1.f - gv) * hcur0[jj];
  }
}

extern "C" void kernel_launch(void* const* d_in, const int* in_sizes, int n_in,
                              void* d_out, int out_size, void* d_ws, size_t ws_size,
                              hipStream_t stream) {
  const float* x        = (const float*)d_in[0];
  const float* h0in     = (const float*)d_in[1];
  const float* c0in     = (const float*)d_in[2];
  const float* Wv       = (const float*)d_in[5];
  const float* Wo       = (const float*)d_in[6];
  const float* Wih      = (const float*)d_in[7];
  const float* Whh      = (const float*)d_in[8];
  const float* b_lstm   = (const float*)d_in[9];
  const float* router_w = (const float*)d_in[10];
  const float* router_b = (const float*)d_in[11];
  const float* expert_w = (const float*)d_in[12];
  const float* expert_b = (const float*)d_in[13];
  const float* dr_w     = (const float*)d_in[14];
  const float* dr_b     = (const float*)d_in[15];
  const float* ram_w    = (const float*)d_in[16];
  const float* ram_b    = (const float*)d_in[17];
  const float* ag_w     = (const float*)d_in[18];
  const float* ag_b     = (const float*)d_in[19];
  float* out = (float*)d_out;
  float* ws  = (float*)d_ws;

  float* dl0 = ws + DL0; float* dl1 = ws + DL1; float* dl3 = ws + DL3;
  float* gt  = ws + GT;
  auto NB = [&](int n) { return ws + NODE_BASE + n * NODESZ; };
  float* fin1 = ws + FIN_BASE;              // N1 finalize
  float* fin3 = ws + FIN_BASE + FINSZ;      // N3 finalize
  float* fin0 = ws + FIN_BASE + 2 * FINSZ;  // N0 finalize (hn slot = hcur0)
  float* rh1 = ws + RH1; float* rf1 = ws + RF1; float* rc1 = ws + RC1;

  auto gemv = [&](const float* xA, const float* xB, int splitPt,
                  const float* W, float* y, int K, int N, int KS,
                  const float* dlA, int maxA, int needA,
                  const float* dlB, int maxB, int needB,
                  const float* cpS, float* cpD, int cpN) {
    k_gemv<<<dim3((N >> 8) * KS), dim3(256), 0, stream>>>(
        xA, xB, splitPt, W, y, K, N, KS, dlA, maxA, needA, dlB, maxB, needB, cpS, cpD, cpN);
  };

  // One node: Wv(+gates copy) -> Wo -> Whh -> expert(+LSTM) -> combine.
  auto node = [&](int n, const float* hv, const float* cv,
                  float* dl, float damping, const float* php, float* hn_out, float* agg_out,
                  const float* dlA, int maxA, int needA,
                  const float* dlB, int maxB, int needB) {
    float* nb = NB(n);
    float* t_hv = nb + O_THV; float* attn = nb + O_ATTN; float* gates = nb + O_GATES;
    float* eo = nb + O_EO; float* so = nb + O_SO; float* cs = nb + O_CS; float* hp = nb + O_HP;
    gemv(hv, hv, H, Wv, t_hv, H, H, 64, dlA, maxA, needA, dlB, maxB, needB, gt, gates, 4 * H);
    gemv(t_hv, t_hv, H, Wo, attn, H, H, 64, dlA, maxA, needA, dlB, maxB, needB, nullptr, nullptr, 0);
    gemv(attn, attn, H, Whh, gates, H, 4 * H, 16, dlA, maxA, needA, dlB, maxB, needB, nullptr, nullptr, 0);
    k_expert<<<dim3(512), dim3(256), 0, stream>>>(gates, cv, expert_w, eo, so, cs,
                                                  dlA, maxA, needA, dlB, maxB, needB);
    if (dl) {
      k_combine<0><<<dim3(8), dim3(256), 0, stream>>>(so, router_w, router_b, eo, hp, dl, dr_w,
                                                      nullptr, 0.f, nullptr, nullptr,
                                                      dlA, maxA, needA, dlB, maxB, needB);
    } else {
      k_combine<1><<<dim3(8), dim3(256), 0, stream>>>(so, router_w, router_b, eo, nullptr, nullptr, nullptr,
                                                      php, damping, hn_out, agg_out,
                                                      dlA, maxA, needA, dlB, maxB, needB);
    }
  };

  // 1. init everything
  k_init<<<dim3(192), dim3(256), 0, stream>>>(ws, b_lstm, expert_b, ram_b, ag_b, dr_b);
  // 2. gates_template += x @ Wih  (node-invariant, hoisted)
  gemv(x, x, H, Wih, gt, H, 4 * H, 16, nullptr, 0, 0, nullptr, 0, 0, nullptr, nullptr, 0);

  // N0
  node(0, h0in, c0in, dl0, 0.f, nullptr, nullptr, nullptr,
       nullptr, 0, 0, nullptr, 0, 0);
  // N1 (pred s0>=1)
  node(1, NB(0) + O_HP, NB(0) + O_CS, dl1, 0.f, nullptr, nullptr, nullptr,
       dl0, 2, 1, nullptr, 0, 0);
  // N2 leaf (pred s0>=1 && s1>=1); combine fuses N1's Ramanujan prep
  node(2, NB(1) + O_HP, NB(1) + O_CS, nullptr, 0.25f, NB(1) + O_HP, fin1 + O_HN, fin1 + O_AGG,
       dl0, 2, 1, dl1, 1, 1);
  // N1 finalize GEMVs + select
  gemv(fin1 + O_AGG, NB(1) + O_HP, H, ram_w, fin1 + O_ANCHOR, 2 * H, H, 64,
       dl0, 2, 1, dl1, 1, 1, nullptr, nullptr, 0);
  gemv(fin1 + O_HN, fin1 + O_ANCHOR, H, ag_w, fin1 + O_GACC, 2 * H, H, 64,
       dl0, 2, 1, dl1, 1, 1, nullptr, nullptr, 0);
  k_fsel<<<dim3(8), dim3(256), 0, stream>>>(dl1, 1,
      fin1 + O_GACC, fin1 + O_ANCHOR, fin1 + O_HN,
      NB(2) + O_SO, NB(2) + O_CS,
      NB(1) + O_HP, NB(1) + O_SO, NB(1) + O_CS,
      rh1, rf1, rc1, dl0, 2, 1);

  // N3 (pred s0>=2), inputs (rh1, rc1)
  node(3, rh1, rc1, dl3, 0.f, nullptr, nullptr, nullptr,
       dl0, 2, 2, nullptr, 0, 0);
  // N4 leaf (pred s0>=2 && s3>=1); combine fuses N3's Ramanujan prep
  node(4, NB(3) + O_HP, NB(3) + O_CS, nullptr, 0.25f, NB(3) + O_HP, fin3 + O_HN, fin3 + O_AGG,
       dl0, 2, 2, dl3, 1, 1);
  gemv(fin3 + O_AGG, NB(3) + O_HP, H, ram_w, fin3 + O_ANCHOR, 2 * H, H, 64,
       dl0, 2, 2, dl3, 1, 1, nullptr, nullptr, 0);
  gemv(fin3 + O_HN, fin3 + O_ANCHOR, H, ag_w, fin3 + O_GACC, 2 * H, H, 64,
       dl0, 2, 2, dl3, 1, 1, nullptr, nullptr, 0);

  // Tail1: N3 select + N0 prep + out F/C
  k_tail1<<<dim3(8), dim3(256), 0, stream>>>(dl0, dl3,
      rh1, rf1, rc1,
      fin3 + O_GACC, fin3 + O_ANCHOR, fin3 + O_HN,
      NB(4) + O_SO, NB(4) + O_CS,
      NB(3) + O_HP, NB(3) + O_SO, NB(3) + O_CS,
      NB(0) + O_HP,
      fin0 + O_AGG, fin0 + O_HN, out, out + 2 * H);
  // N0 finalize GEMVs (pred s0>=1)
  gemv(fin0 + O_AGG, NB(0) + O_HP, H, ram_w, fin0 + O_ANCHOR, 2 * H, H, 64,
       dl0, 2, 1, nullptr, 0, 0, nullptr, nullptr, 0);
  gemv(fin0 + O_HN, fin0 + O_ANCHOR, H, ag_w, fin0 + O_GACC, 2 * H, H, 64,
       dl0, 2, 1, nullptr, 0, 0, nullptr, nullptr, 0);
  // Tail2: final h (or s0==0 leaf passthrough)
  k_tail2<<<dim3(8), dim3(256), 0, stream>>>(dl0,
      NB(0) + O_SO, NB(0) + O_HP, NB(0) + O_CS,
      fin0 + O_GACC, fin0 + O_ANCHOR, fin0 + O_HN, out);
}